// Round 4
// baseline (906.969 us; speedup 1.0000x reference)
//
#include <hip/hip_runtime.h>

#define BATCH 131072

typedef __attribute__((ext_vector_type(8))) __bf16 bf16x8;
typedef __attribute__((ext_vector_type(16))) float f32x16;

__constant__ int FOFF[23] = {0,4,8,12,16,20,24,28,32,36,40,44,48,50,52,53,57,58,59,60,61,62,63};
__constant__ int FDIM[23] = {4,4,4,4,4,4,4,4,4,4,4,4,2,2,1,4,1,1,1,1,1,1,2};

__device__ __forceinline__ unsigned short f2bf(float f){
  unsigned int u = __float_as_uint(f);
  u += 0x7fffu + ((u>>16)&1u);   // RNE
  return (unsigned short)(u>>16);
}
__device__ __forceinline__ unsigned int packpair(float a, float b){
  return (unsigned int)f2bf(a) | ((unsigned int)f2bf(b)<<16);
}
__device__ __forceinline__ float bflo(unsigned int u){ return __uint_as_float(u<<16); }
__device__ __forceinline__ float bfhi(unsigned int u){ return __uint_as_float(u & 0xffff0000u); }

// ---------------- prep: pack W1..W5 into MFMA-B fragment-linear bf16 layout ----------------
// layout: frag index = (ks*6 + nt)*64 + lane ; j in 0..7 within frag; value = W[k][n],
// k=ks*16+(lane>>5)*8+j, n=nt*32+(lane&31); zero-padded. W1: 15 ksteps; W2..5: 11. N 164->192.
__global__ void prep_weights(const float* __restrict__ W1, const float* __restrict__ W2,
    const float* __restrict__ W3, const float* __restrict__ W4, const float* __restrict__ W5,
    unsigned short* __restrict__ wpack){
  int idx = blockIdx.x*256 + threadIdx.x;
  if (idx >= 22656) return;
  const float* W; int rel; int Kd;
  if (idx < 5760){ W = W1; rel = idx; Kd = 230; }
  else {
    int r2 = idx - 5760;
    int li = r2 / 4224; rel = r2 - li*4224; Kd = 164;
    W = (li==0)?W2:((li==1)?W3:((li==2)?W4:W5));
  }
  int lane = rel & 63, rem = rel >> 6;
  int nt = rem % 6, ks = rem / 6;
  int n  = nt*32 + (lane&31);
  int k0 = ks*16 + ((lane>>5)<<3);
  unsigned int v[4];
  #pragma unroll
  for (int p=0;p<4;p++){
    int ka = k0 + 2*p, kb = ka+1;
    float fa = (ka<Kd && n<164) ? W[ka*164+n] : 0.f;
    float fb = (kb<Kd && n<164) ? W[kb*164+n] : 0.f;
    v[p] = packpair(fa, fb);
  }
  *(uint4*)(wpack + (size_t)idx*8) = make_uint4(v[0],v[1],v[2],v[3]);
}

// ---------------- attention chunk: ONE query row of one sample ----------------
// C=1 keeps peak live floats ~45 so the 64-VGPR clamp (needed for 2 blocks/CU)
// holds without scratch spill. Callers MUST fence consecutive chunks with
// sched_barrier(0) or the scheduler merges their live ranges (measured: spill).
__device__ __forceinline__ void attn_chunk1(int s, int i,
    const unsigned int* hp, const float* sw, unsigned int* z32){
  // ---- g = h_i * M (M = Wq Wk^T / sqrt(10), broadcast reads from LDS) ----
  float g[10];
  #pragma unroll
  for (int d=0;d<10;d++) g[d]=0.f;
  {
    float hi[10];
    #pragma unroll
    for (int p=0;p<5;p++){
      unsigned int u = hp[(i*5+p)*64 + s];
      hi[2*p] = bflo(u); hi[2*p+1] = bfhi(u);
    }
    #pragma unroll
    for (int e=0;e<10;e++){
      float he = hi[e];
      #pragma unroll
      for (int d=0;d<10;d++) g[d] += he*sw[1840 + e*12 + d];
    }
  }
  // ---- single-pass unnormalized softmax over 23 keys ----
  float st[10]; float tau = 0.f;
  #pragma unroll
  for (int d=0;d<10;d++) st[d]=0.f;
  for (int j=0;j<23;j++){
    float hj[10];
    #pragma unroll
    for (int p=0;p<5;p++){
      unsigned int u = hp[(j*5+p)*64 + s];
      hj[2*p]=bflo(u); hj[2*p+1]=bfhi(u);
    }
    float l = 0.f;
    #pragma unroll
    for (int d=0;d<10;d++) l += g[d]*hj[d];
    float e = __expf(l);
    tau += e;
    #pragma unroll
    for (int d=0;d<10;d++) st[d] += e*hj[d];
  }
  {
    float inv = 1.f/tau;
    #pragma unroll
    for (int d=0;d<10;d++) st[d] *= inv;
  }
  // ---- ctx = st * Wv (Wv broadcast from LDS) ----
  float ct[10];
  #pragma unroll
  for (int d=0;d<10;d++) ct[d]=0.f;
  #pragma unroll
  for (int e=0;e<10;e++){
    float se = st[e];
    #pragma unroll
    for (int d=0;d<10;d++) ct[d] += se*sw[1960 + e*12 + d];
  }
  // ---- residual + pack to z ----
  #pragma unroll
  for (int p=0;p<5;p++){
    unsigned int u = hp[(i*5+p)*64 + s];
    float z0 = bflo(u) + ct[2*p];
    float z1 = bfhi(u) + ct[2*p+1];
    z32[s*124 + i*5 + p] = packpair(z0,z1);
  }
}

// ---------------- MFMA MLP inner: NT n-tiles for one 32-row M-tile ----------------
template<int KSTEPS, int NT>
__device__ __forceinline__ void mlp_tiles(const unsigned short* abase, const bf16x8* wb,
    const float* __restrict__ bias, unsigned short* out16, int nt0, int colb, int rowb){
  f32x16 acc[NT];
  #pragma unroll
  for (int nt=0; nt<NT; ++nt)
    #pragma unroll
    for (int r=0;r<16;r++) acc[nt][r]=0.f;
  #pragma unroll
  for (int ks=0; ks<KSTEPS; ++ks){
    bf16x8 a = *(const bf16x8*)(abase + ks*16);
    const bf16x8* wk = wb + ks*(6*64);
    #pragma unroll
    for (int nt=0; nt<NT; ++nt)
      acc[nt] = __builtin_amdgcn_mfma_f32_32x32x16_bf16(a, wk[nt*64], acc[nt], 0,0,0);
  }
  #pragma unroll
  for (int nt=0; nt<NT; ++nt){
    int n = (nt0+nt)*32 + colb;
    float b = (n<164) ? bias[n] : 0.f;
    #pragma unroll
    for (int r=0;r<16;r++){
      int row = rowb + (r&3) + 8*(r>>2);
      float v = fmaxf(acc[nt][r] + b, 0.f);
      out16[row*200 + n] = f2bf(v);
    }
  }
}

// 64 rows, 8 waves: 2 M-tiles x N-groups {2,2,1,1} of the 6 N-tiles (N 164->192)
template<int KSTEPS>
__device__ __forceinline__ void mlp_layer(const unsigned short* in16, int inPitch,
    const bf16x8* __restrict__ wp, const float* __restrict__ bias,
    unsigned short* out16, int t){
  const int lane = t & 63;
  const int w = t >> 6;      // 0..7
  const int mt = w & 1;      // 2 M-tiles of 32
  const int ng = w >> 1;     // 0..3
  const unsigned short* abase = in16 + (mt*32 + (lane&31))*inPitch + ((lane>>5)<<3);
  const int colb = lane&31;
  const int rowb = mt*32 + 4*(lane>>5);
  if (ng < 2){
    const int nt0 = 2*ng;                       // tiles {0,1} or {2,3}
    mlp_tiles<KSTEPS,2>(abase, wp + nt0*64 + lane, bias, out16, nt0, colb, rowb);
  } else {
    const int nt0 = ng + 2;                     // tile {4} or {5}
    mlp_tiles<KSTEPS,1>(abase, wp + nt0*64 + lane, bias, out16, nt0, colb, rowb);
  }
}

// ---------------- fused main kernel: 64 samples / workgroup, 2 blocks/CU ----------------
// launch_bounds arg2=4 -> compiler targets 64 VGPR: empirically REQUIRED for 2 blocks/CU
// residency (VGPR 68 @ arg2=2 dropped to 1 block/CU, 42%->23% occupancy). Attention is
// C=1-chunked so 64 VGPR holds WITHOUT spill (chunk<3> at this clamp spilled 200MB).
__global__ __launch_bounds__(512, 4) void actor_main(
    const float* __restrict__ xg, const float* __restrict__ Wproj, const float* __restrict__ bproj,
    const float* __restrict__ Wq, const float* __restrict__ Wk, const float* __restrict__ Wv,
    const float* __restrict__ b1, const float* __restrict__ b2, const float* __restrict__ b3,
    const float* __restrict__ b4, const float* __restrict__ b5,
    const float* __restrict__ Wmove, const float* __restrict__ bmove,
    const float* __restrict__ Wmark, const float* __restrict__ bmark,
    const unsigned short* __restrict__ wpack, float* __restrict__ out)
{
  // LDS: [0,31744) z-buffer (64 x pitch 248 bf16) / x-stage union;
  //      [31744,61184) h SoA pairs (23*5*64 u32) / act buffer (64 x pitch 200 bf16);
  //      [61184,71472) small weights. Total 71,472 B -> 2 workgroups/CU.
  __shared__ __align__(16) unsigned char LDS[71472];
  float* xb = (float*)LDS;
  unsigned int* z32 = (unsigned int*)LDS;
  unsigned short* z16 = (unsigned short*)LDS;
  unsigned int* hp = (unsigned int*)(LDS + 31744);
  unsigned short* a16 = (unsigned short*)(LDS + 31744);
  float* sw = (float*)(LDS + 61184);
  unsigned int* swu = (unsigned int*)(LDS + 61184);

  const int t = threadIdx.x;
  const int S0 = blockIdx.x*64;

  // ---- P0: stage x (vectorized, coalesced) + pad zeros + small weights ----
  {
    const float4* src4 = (const float4*)(xg + (size_t)S0*65);
    float4* x4 = (float4*)xb;
    for (int i=t; i<1040; i+=512) x4[i] = src4[i];   // 64*65 = 4160 floats
    if (t<8) xb[4160+t] = 0.f;   // proj over-read pad (zero-weight lanes)
  }
  for (int idx=t; idx<2572; idx+=512){
    if (idx < 1840){                 // proj packed: [o][0..3]=w, [4]=bias
      int o = idx>>3, u = idx&7;
      int fi = o/10;
      float v = 0.f;
      if (u<4){ if (u < FDIM[fi]) v = Wproj[(FOFF[fi]+u)*230 + o]; }
      else if (u==4) v = bproj[o];
      sw[idx] = v;
    } else if (idx < 1960){          // M = Wq*Wk^T/sqrt(10), [10][12]
      int r = idx-1840, e = r/12, d = r-12*e;
      float v = 0.f;
      if (d<10){ float ssum=0.f;
        #pragma unroll
        for (int k2=0;k2<10;k2++) ssum += Wq[e*10+k2]*Wk[d*10+k2];
        v = ssum*0.31622776601683794f; }
      sw[idx] = v;
    } else if (idx < 2080){          // Wv [10][12]
      int r = idx-1960, e = r/12, d = r-12*e;
      sw[idx] = (d<10)? Wv[e*10+d] : 0.f;
    } else {                         // head weights, bf16 pairs [6][82]
      int r = idx-2080, o = r/82, kp = r-82*o;
      float w0, w1;
      if (o<5){ w0 = Wmove[(2*kp)*5+o]; w1 = Wmove[(2*kp+1)*5+o]; }
      else    { w0 = Wmark[2*kp];       w1 = Wmark[2*kp+1]; }
      swu[idx] = packpair(w0,w1);
    }
  }
  __syncthreads();

  // ---- P1: block-diagonal projection -> h SoA bf16 pairs hp[(j*5+p)*64+s] ----
  for (int L=t; L<7360; L+=512){
    int s = L & 63, jp = L>>6;
    int j = jp/5, p = jp-5*j;
    int o0 = j*10 + 2*p;
    int roff = FOFF[j];
    float a0 = sw[o0*8+4], a1 = sw[o0*8+12];
    #pragma unroll
    for (int u=0;u<4;u++){
      float xv = xb[s*65 + roff + u];
      a0 += xv * sw[o0*8+u];
      a1 += xv * sw[o0*8+8+u];
    }
    hp[L] = packpair(a0,a1);
  }
  __syncthreads();

  // ---- P2: attention (8 threads/sample; three fenced C=1 chunks each) ----
  {
    const int s = t & 63;
    const int q = t >> 6;            // wave-uniform
    if (q < 7){
      attn_chunk1(s, 3*q,   hp, sw, z32);
      __builtin_amdgcn_sched_barrier(0);   // pinch: keep chunk live-ranges disjoint
      attn_chunk1(s, 3*q+1, hp, sw, z32);
      __builtin_amdgcn_sched_barrier(0);
      attn_chunk1(s, 3*q+2, hp, sw, z32);
      __builtin_amdgcn_sched_barrier(0);
    } else {
      attn_chunk1(s, 21, hp, sw, z32);
      __builtin_amdgcn_sched_barrier(0);
      attn_chunk1(s, 22, hp, sw, z32);
      __builtin_amdgcn_sched_barrier(0);
      // wave 7 is lighter: it zeroes the z pad cols 230..239 (K padded to 240)
      for (int idx=s; idx<320; idx+=64){
        int ss = idx/5, pc = idx-5*ss;
        z32[ss*124 + 115+pc] = 0u;
      }
    }
  }
  __syncthreads();

  // ---- P3: MLP, 5 layers of MFMA, ping-pong LDS act buffers ----
  const bf16x8* wpk = (const bf16x8*)wpack;
  mlp_layer<15>(z16, 248, wpk,          b1, a16, t); __syncthreads();
  mlp_layer<11>(a16, 200, wpk + 5760,   b2, z16, t); __syncthreads();
  mlp_layer<11>(z16, 200, wpk + 9984,   b3, a16, t); __syncthreads();
  mlp_layer<11>(a16, 200, wpk + 14208,  b4, z16, t); __syncthreads();
  mlp_layer<11>(z16, 200, wpk + 18432,  b5, a16, t); __syncthreads();

  // ---- P4: heads (move[5] + mark[1]) ----
  for (int idx=t; idx<384; idx+=512){
    int s2 = idx & 63, o = idx>>6;
    const unsigned int* ar = (const unsigned int*)(a16 + s2*200);
    const unsigned int* wr = swu + 2080 + o*82;
    float acc = 0.f;
    for (int kp=0; kp<82; ++kp){
      unsigned int ua = ar[kp], uw = wr[kp];
      acc += bflo(ua)*bflo(uw) + bfhi(ua)*bfhi(uw);
    }
    acc += (o<5)? bmove[o] : bmark[0];
    if (o<5) out[(size_t)(S0+s2)*5 + o] = acc;
    else     out[(size_t)BATCH*5 + S0 + s2] = acc;
  }
}

extern "C" void kernel_launch(void* const* d_in, const int* in_sizes, int n_in,
                              void* d_out, int out_size, void* d_ws, size_t ws_size,
                              hipStream_t stream){
  (void)in_sizes; (void)n_in; (void)out_size; (void)ws_size;
  const float* x     = (const float*)d_in[0];
  const float* Wproj = (const float*)d_in[1];
  const float* bproj = (const float*)d_in[2];
  const float* Wq    = (const float*)d_in[3];
  const float* Wk    = (const float*)d_in[4];
  const float* Wv    = (const float*)d_in[5];
  const float* W1    = (const float*)d_in[6];
  const float* b1    = (const float*)d_in[7];
  const float* W2    = (const float*)d_in[8];
  const float* b2    = (const float*)d_in[9];
  const float* W3    = (const float*)d_in[10];
  const float* b3    = (const float*)d_in[11];
  const float* W4    = (const float*)d_in[12];
  const float* b4    = (const float*)d_in[13];
  const float* W5    = (const float*)d_in[14];
  const float* b5    = (const float*)d_in[15];
  const float* Wmove = (const float*)d_in[16];
  const float* bmove = (const float*)d_in[17];
  const float* Wmark = (const float*)d_in[18];
  const float* bmark = (const float*)d_in[19];
  unsigned short* wpack = (unsigned short*)d_ws;

  prep_weights<<<89, 256, 0, stream>>>(W1, W2, W3, W4, W5, wpack);
  actor_main<<<2048, 512, 0, stream>>>(x, Wproj, bproj, Wq, Wk, Wv,
      b1, b2, b3, b4, b5, Wmove, bmove, Wmark, bmark, wpack, (float*)d_out);
}

// Round 5
// 292.986 us; speedup vs baseline: 3.0956x; 3.0956x over previous
//
#include <hip/hip_runtime.h>

#define BATCH 131072

typedef __attribute__((ext_vector_type(8))) __bf16 bf16x8;
typedef __attribute__((ext_vector_type(16))) float f32x16;

__constant__ int FOFF[23] = {0,4,8,12,16,20,24,28,32,36,40,44,48,50,52,53,57,58,59,60,61,62,63};
__constant__ int FDIM[23] = {4,4,4,4,4,4,4,4,4,4,4,4,2,2,1,4,1,1,1,1,1,1,2};

__device__ __forceinline__ unsigned short f2bf(float f){
  unsigned int u = __float_as_uint(f);
  u += 0x7fffu + ((u>>16)&1u);   // RNE
  return (unsigned short)(u>>16);
}
__device__ __forceinline__ unsigned int packpair(float a, float b){
  return (unsigned int)f2bf(a) | ((unsigned int)f2bf(b)<<16);
}
__device__ __forceinline__ float bflo(unsigned int u){ return __uint_as_float(u<<16); }
__device__ __forceinline__ float bfhi(unsigned int u){ return __uint_as_float(u & 0xffff0000u); }

// ---------------- prep: pack W1..W5 into MFMA-B fragment-linear bf16 layout ----------------
// layout: frag index = (ks*6 + nt)*64 + lane ; j in 0..7 within frag; value = W[k][n],
// k=ks*16+(lane>>5)*8+j, n=nt*32+(lane&31); zero-padded. W1: 15 ksteps; W2..5: 11. N 164->192.
__global__ void prep_weights(const float* __restrict__ W1, const float* __restrict__ W2,
    const float* __restrict__ W3, const float* __restrict__ W4, const float* __restrict__ W5,
    unsigned short* __restrict__ wpack){
  int idx = blockIdx.x*256 + threadIdx.x;
  if (idx >= 22656) return;
  const float* W; int rel; int Kd;
  if (idx < 5760){ W = W1; rel = idx; Kd = 230; }
  else {
    int r2 = idx - 5760;
    int li = r2 / 4224; rel = r2 - li*4224; Kd = 164;
    W = (li==0)?W2:((li==1)?W3:((li==2)?W4:W5));
  }
  int lane = rel & 63, rem = rel >> 6;
  int nt = rem % 6, ks = rem / 6;
  int n  = nt*32 + (lane&31);
  int k0 = ks*16 + ((lane>>5)<<3);
  unsigned int v[4];
  #pragma unroll
  for (int p=0;p<4;p++){
    int ka = k0 + 2*p, kb = ka+1;
    float fa = (ka<Kd && n<164) ? W[ka*164+n] : 0.f;
    float fb = (kb<Kd && n<164) ? W[kb*164+n] : 0.f;
    v[p] = packpair(fa, fb);
  }
  *(uint4*)(wpack + (size_t)idx*8) = make_uint4(v[0],v[1],v[2],v[3]);
}

// ---------------- attention chunk: C (<=2) query rows of one sample, h-pitch 128 ----------------
// Runtime C + if(c<C) guards: this shape allocates ~68 VGPR spill-free (proven R0/R3).
// Do NOT template C or drop the guards (scheduler merges chunk live ranges -> 261 MB spill, R2).
// Do NOT let the VGPR budget hit 64 (st[]/g[] arrays go to scratch -> 2.87 GB traffic, R4).
__device__ __forceinline__ void attn_chunk2(int s, int ibase, int C,
    const unsigned int* hp, const float* sw, unsigned int* z32){
  // ---- g = h_i * M (M = Wq Wk^T / sqrt(10), broadcast reads from LDS) ----
  float g[2][10];
  #pragma unroll
  for (int c=0;c<2;c++)
    #pragma unroll
    for (int d=0;d<10;d++) g[c][d]=0.f;
  {
    float hi[2][10];
    #pragma unroll
    for (int c=0;c<2;c++) if (c<C){
      #pragma unroll
      for (int p=0;p<5;p++){
        unsigned int u = hp[((ibase+c)*5+p)*128 + s];
        hi[c][2*p] = bflo(u); hi[c][2*p+1] = bfhi(u);
      }
    }
    #pragma unroll
    for (int e=0;e<10;e++){
      float m[10];
      #pragma unroll
      for (int d=0;d<10;d++) m[d] = sw[1840 + e*12 + d];
      #pragma unroll
      for (int c=0;c<2;c++) if (c<C){
        float he = hi[c][e];
        #pragma unroll
        for (int d=0;d<10;d++) g[c][d] += he*m[d];
      }
    }
  }
  // ---- single-pass unnormalized softmax over 23 keys ----
  float st[2][10]; float tau[2];
  #pragma unroll
  for (int c=0;c<2;c++){
    tau[c]=0.f;
    #pragma unroll
    for (int d=0;d<10;d++) st[c][d]=0.f;
  }
  for (int j=0;j<23;j++){
    float hj[10];
    #pragma unroll
    for (int p=0;p<5;p++){
      unsigned int u = hp[(j*5+p)*128 + s];
      hj[2*p]=bflo(u); hj[2*p+1]=bfhi(u);
    }
    #pragma unroll
    for (int c=0;c<2;c++) if (c<C){
      float l = 0.f;
      #pragma unroll
      for (int d=0;d<10;d++) l += g[c][d]*hj[d];
      float e = __expf(l);
      tau[c] += e;
      #pragma unroll
      for (int d=0;d<10;d++) st[c][d] += e*hj[d];
    }
  }
  #pragma unroll
  for (int c=0;c<2;c++) if (c<C){
    float inv = 1.f/tau[c];
    #pragma unroll
    for (int d=0;d<10;d++) st[c][d] *= inv;
  }
  // ---- ctx = st * Wv (Wv broadcast from LDS, shared across the C rows) ----
  float ct[2][10];
  #pragma unroll
  for (int c=0;c<2;c++)
    #pragma unroll
    for (int d=0;d<10;d++) ct[c][d]=0.f;
  #pragma unroll
  for (int e=0;e<10;e++){
    float wv[10];
    #pragma unroll
    for (int d=0;d<10;d++) wv[d] = sw[1960 + e*12 + d];
    #pragma unroll
    for (int c=0;c<2;c++) if (c<C){
      float se = st[c][e];
      #pragma unroll
      for (int d=0;d<10;d++) ct[c][d] += se*wv[d];
    }
  }
  // ---- residual + pack to z ----
  #pragma unroll
  for (int c=0;c<2;c++) if (c<C){
    int i = ibase+c;
    #pragma unroll
    for (int p=0;p<5;p++){
      unsigned int u = hp[(i*5+p)*128 + s];
      float z0 = bflo(u) + ct[c][2*p];
      float z1 = bfhi(u) + ct[c][2*p+1];
      z32[s*124 + i*5 + p] = packpair(z0,z1);
    }
  }
}

// ---------------- MFMA MLP inner: NT n-tiles for one 32-row M-tile ----------------
template<int KSTEPS, int NT>
__device__ __forceinline__ void mlp_tiles(const unsigned short* abase, const bf16x8* wb,
    const float* __restrict__ bias, unsigned short* out16, int nt0, int colb, int rowb){
  f32x16 acc[NT];
  #pragma unroll
  for (int nt=0; nt<NT; ++nt)
    #pragma unroll
    for (int r=0;r<16;r++) acc[nt][r]=0.f;
  #pragma unroll
  for (int ks=0; ks<KSTEPS; ++ks){
    bf16x8 a = *(const bf16x8*)(abase + ks*16);
    const bf16x8* wk = wb + ks*(6*64);
    #pragma unroll
    for (int nt=0; nt<NT; ++nt)
      acc[nt] = __builtin_amdgcn_mfma_f32_32x32x16_bf16(a, wk[nt*64], acc[nt], 0,0,0);
  }
  #pragma unroll
  for (int nt=0; nt<NT; ++nt){
    int n = (nt0+nt)*32 + colb;
    float b = (n<164) ? bias[n] : 0.f;
    #pragma unroll
    for (int r=0;r<16;r++){
      int row = rowb + (r&3) + 8*(r>>2);
      float v = fmaxf(acc[nt][r] + b, 0.f);
      out16[row*200 + n] = f2bf(v);
    }
  }
}

// 128 rows, 16 waves: 4 M-tiles x 4 N-groups {2,2,1,1} of the 6 N-tiles (N 164->192)
template<int KSTEPS>
__device__ __forceinline__ void mlp_layer(const unsigned short* in16, int inPitch,
    const bf16x8* __restrict__ wp, const float* __restrict__ bias,
    unsigned short* out16, int t){
  const int lane = t & 63;
  const int w = t >> 6;      // 0..15
  const int mt = w & 3;      // 4 M-tiles of 32
  const int ng = w >> 2;     // 0..3
  const unsigned short* abase = in16 + (mt*32 + (lane&31))*inPitch + ((lane>>5)<<3);
  const int colb = lane&31;
  const int rowb = mt*32 + 4*(lane>>5);
  if (ng < 2){
    const int nt0 = 2*ng;                       // tiles {0,1} or {2,3}
    mlp_tiles<KSTEPS,2>(abase, wp + nt0*64 + lane, bias, out16, nt0, colb, rowb);
  } else {
    const int nt0 = ng + 2;                     // tile {4} or {5}
    mlp_tiles<KSTEPS,1>(abase, wp + nt0*64 + lane, bias, out16, nt0, colb, rowb);
  }
}

// ---------------- fused main kernel: 128 samples / 1024-thread workgroup ----------------
// 16 waves/CU from ONE block: wg=1024 forces the compiler to <=128 VGPR (4 waves/SIMD),
// actual demand ~68 (R3) -> spill-free, and occupancy doubles vs the 512-thread variant
// without touching the 64-VGPR spill cliff (64 always spills: R1 200MB, R4 2.87GB).
__global__ __launch_bounds__(1024, 1) void actor_main(
    const float* __restrict__ xg, const float* __restrict__ Wproj, const float* __restrict__ bproj,
    const float* __restrict__ Wq, const float* __restrict__ Wk, const float* __restrict__ Wv,
    const float* __restrict__ b1, const float* __restrict__ b2, const float* __restrict__ b3,
    const float* __restrict__ b4, const float* __restrict__ b5,
    const float* __restrict__ Wmove, const float* __restrict__ bmove,
    const float* __restrict__ Wmark, const float* __restrict__ bmark,
    const unsigned short* __restrict__ wpack, float* __restrict__ out)
{
  // LDS: [0,63488) z-buffer (128 x pitch 248 bf16) / x-stage union;
  //      [63488,122368) h SoA pairs (23*5*128 u32) / act buffer (128 x pitch 200 bf16);
  //      [122368,132656) small weights. Total 132,656 B -> 1 workgroup/CU, 16 waves.
  __shared__ __align__(16) unsigned char LDS[132656];
  float* xb = (float*)LDS;
  unsigned int* z32 = (unsigned int*)LDS;
  unsigned short* z16 = (unsigned short*)LDS;
  unsigned int* hp = (unsigned int*)(LDS + 63488);
  unsigned short* a16 = (unsigned short*)(LDS + 63488);
  float* sw = (float*)(LDS + 122368);
  unsigned int* swu = (unsigned int*)(LDS + 122368);

  const int t = threadIdx.x;
  const int S0 = blockIdx.x*128;

  // ---- P0: stage x (vectorized, coalesced) + pad zeros + small weights ----
  {
    const float4* src4 = (const float4*)(xg + (size_t)S0*65);
    float4* x4 = (float4*)xb;
    for (int i=t; i<2080; i+=1024) x4[i] = src4[i];   // 128*65 = 8320 floats
    if (t<8) xb[8320+t] = 0.f;   // proj over-read pad (zero-weight lanes)
  }
  for (int idx=t; idx<2572; idx+=1024){
    if (idx < 1840){                 // proj packed: [o][0..3]=w, [4]=bias
      int o = idx>>3, u = idx&7;
      int fi = o/10;
      float v = 0.f;
      if (u<4){ if (u < FDIM[fi]) v = Wproj[(FOFF[fi]+u)*230 + o]; }
      else if (u==4) v = bproj[o];
      sw[idx] = v;
    } else if (idx < 1960){          // M = Wq*Wk^T/sqrt(10), [10][12]
      int r = idx-1840, e = r/12, d = r-12*e;
      float v = 0.f;
      if (d<10){ float ssum=0.f;
        #pragma unroll
        for (int k2=0;k2<10;k2++) ssum += Wq[e*10+k2]*Wk[d*10+k2];
        v = ssum*0.31622776601683794f; }
      sw[idx] = v;
    } else if (idx < 2080){          // Wv [10][12]
      int r = idx-1960, e = r/12, d = r-12*e;
      sw[idx] = (d<10)? Wv[e*10+d] : 0.f;
    } else {                         // head weights, bf16 pairs [6][82]
      int r = idx-2080, o = r/82, kp = r-82*o;
      float w0, w1;
      if (o<5){ w0 = Wmove[(2*kp)*5+o]; w1 = Wmove[(2*kp+1)*5+o]; }
      else    { w0 = Wmark[2*kp];       w1 = Wmark[2*kp+1]; }
      swu[idx] = packpair(w0,w1);
    }
  }
  __syncthreads();

  // ---- P1: block-diagonal projection -> h SoA bf16 pairs hp[(j*5+p)*128+s] ----
  for (int L=t; L<14720; L+=1024){
    int s = L & 127, jp = L>>7;
    int j = jp/5, p = jp-5*j;
    int o0 = j*10 + 2*p;
    int roff = FOFF[j];
    float a0 = sw[o0*8+4], a1 = sw[o0*8+12];
    #pragma unroll
    for (int u=0;u<4;u++){
      float xv = xb[s*65 + roff + u];
      a0 += xv * sw[o0*8+u];
      a1 += xv * sw[o0*8+8+u];
    }
    hp[L] = packpair(a0,a1);
  }
  __syncthreads();

  // ---- P2: attention (8 threads/sample; 2 rows then 1 row, schedule-fenced) ----
  {
    const int s = t & 127;
    const int q = t >> 7;            // 0..7, wave-uniform (128-thread granules)
    const int ib0 = (q<7) ? 3*q : 21;
    attn_chunk2(s, ib0, 2, hp, sw, z32);           // rows {3q,3q+1} or {21,22}
    __builtin_amdgcn_sched_barrier(0);             // pinch point: don't interleave chunks
    if (q < 7){
      attn_chunk2(s, 3*q+2, 1, hp, sw, z32);       // row 3q+2
    } else {
      // wave-group 7 is lighter: zero z pad cols 230..239 (K padded to 240 for layer1)
      for (int idx=s; idx<640; idx+=128){
        int ss = idx/5, pc = idx-5*ss;
        z32[ss*124 + 115+pc] = 0u;
      }
    }
    __builtin_amdgcn_sched_barrier(0);
  }
  __syncthreads();

  // ---- P3: MLP, 5 layers of MFMA, ping-pong LDS act buffers ----
  const bf16x8* wpk = (const bf16x8*)wpack;
  mlp_layer<15>(z16, 248, wpk,          b1, a16, t); __syncthreads();
  mlp_layer<11>(a16, 200, wpk + 5760,   b2, z16, t); __syncthreads();
  mlp_layer<11>(z16, 200, wpk + 9984,   b3, a16, t); __syncthreads();
  mlp_layer<11>(a16, 200, wpk + 14208,  b4, z16, t); __syncthreads();
  mlp_layer<11>(z16, 200, wpk + 18432,  b5, a16, t); __syncthreads();

  // ---- P4: heads (move[5] + mark[1]) ----
  if (t < 768){
    int s2 = t & 127, o = t>>7;
    const unsigned int* ar = (const unsigned int*)(a16 + s2*200);
    const unsigned int* wr = swu + 2080 + o*82;
    float acc = 0.f;
    for (int kp=0; kp<82; ++kp){
      unsigned int ua = ar[kp], uw = wr[kp];
      acc += bflo(ua)*bflo(uw) + bfhi(ua)*bfhi(uw);
    }
    acc += (o<5)? bmove[o] : bmark[0];
    if (o<5) out[(size_t)(S0+s2)*5 + o] = acc;
    else     out[(size_t)BATCH*5 + S0 + s2] = acc;
  }
}

extern "C" void kernel_launch(void* const* d_in, const int* in_sizes, int n_in,
                              void* d_out, int out_size, void* d_ws, size_t ws_size,
                              hipStream_t stream){
  (void)in_sizes; (void)n_in; (void)out_size; (void)ws_size;
  const float* x     = (const float*)d_in[0];
  const float* Wproj = (const float*)d_in[1];
  const float* bproj = (const float*)d_in[2];
  const float* Wq    = (const float*)d_in[3];
  const float* Wk    = (const float*)d_in[4];
  const float* Wv    = (const float*)d_in[5];
  const float* W1    = (const float*)d_in[6];
  const float* b1    = (const float*)d_in[7];
  const float* W2    = (const float*)d_in[8];
  const float* b2    = (const float*)d_in[9];
  const float* W3    = (const float*)d_in[10];
  const float* b3    = (const float*)d_in[11];
  const float* W4    = (const float*)d_in[12];
  const float* b4    = (const float*)d_in[13];
  const float* W5    = (const float*)d_in[14];
  const float* b5    = (const float*)d_in[15];
  const float* Wmove = (const float*)d_in[16];
  const float* bmove = (const float*)d_in[17];
  const float* Wmark = (const float*)d_in[18];
  const float* bmark = (const float*)d_in[19];
  unsigned short* wpack = (unsigned short*)d_ws;

  prep_weights<<<89, 256, 0, stream>>>(W1, W2, W3, W4, W5, wpack);
  actor_main<<<1024, 1024, 0, stream>>>(x, Wproj, bproj, Wq, Wk, Wv,
      b1, b2, b3, b4, b5, Wmove, bmove, Wmark, bmark, wpack, (float*)d_out);
}